// Round 3
// baseline (4443.217 us; speedup 1.0000x reference)
//
#include <hip/hip_runtime.h>

constexpr int N = 50000;
constexpr int E = 800000;
constexpr int D = 128;
constexpr int MASKN = 25000;
constexpr int SCAN_CHUNK = 1024;
constexpr int NB_SCAN = (N + SCAN_CHUNK - 1) / SCAN_CHUNK; // 49

#define FMA4(acc, s, b)                                                        \
    acc.x = fmaf(s, b.x, acc.x);                                               \
    acc.y = fmaf(s, b.y, acc.y);                                               \
    acc.z = fmaf(s, b.z, acc.z);                                               \
    acc.w = fmaf(s, b.w, acc.w)

#define ADD4(acc, v)                                                           \
    acc.x += v.x;                                                              \
    acc.y += v.y;                                                              \
    acc.z += v.z;                                                              \
    acc.w += v.w

// ---------------- CSR build ----------------

__global__ void k_count(const int* __restrict__ src, const int* __restrict__ dst,
                        int* __restrict__ cnt_src, int* __restrict__ cnt_dst) {
    int e = blockIdx.x * blockDim.x + threadIdx.x;
    if (e < E) {
        atomicAdd(&cnt_src[src[e]], 1);
        atomicAdd(&cnt_dst[dst[e]], 1);
    }
}

__global__ void k_scan1(const int* __restrict__ cnt, int* __restrict__ bsum) {
    __shared__ int sh[256];
    int base = blockIdx.x * SCAN_CHUNK;
    int t = threadIdx.x;
    int s = 0;
#pragma unroll
    for (int j = 0; j < 4; ++j) {
        int i = base + t * 4 + j;
        if (i < N) s += cnt[i];
    }
    sh[t] = s;
    __syncthreads();
    for (int o = 128; o > 0; o >>= 1) {
        if (t < o) sh[t] += sh[t + o];
        __syncthreads();
    }
    if (t == 0) bsum[blockIdx.x] = sh[0];
}

__global__ void k_scan2(int* __restrict__ bsum, int* __restrict__ row_ptr) {
    if (threadIdx.x == 0 && blockIdx.x == 0) {
        int run = 0;
        for (int i = 0; i < NB_SCAN; ++i) {
            int v = bsum[i];
            bsum[i] = run;
            run += v;
        }
        row_ptr[N] = run; // == E
    }
}

__global__ void k_scan3(const int* __restrict__ cnt, const int* __restrict__ bsum,
                        int* __restrict__ row_ptr) {
    __shared__ int sh[256];
    int base = blockIdx.x * SCAN_CHUNK;
    int t = threadIdx.x;
    int v[4];
    int tot = 0;
#pragma unroll
    for (int j = 0; j < 4; ++j) {
        int i = base + t * 4 + j;
        v[j] = (i < N) ? cnt[i] : 0;
        tot += v[j];
    }
    sh[t] = tot;
    __syncthreads();
    for (int o = 1; o < 256; o <<= 1) {
        int y = (t >= o) ? sh[t - o] : 0;
        __syncthreads();
        sh[t] += y;
        __syncthreads();
    }
    int excl = sh[t] - tot;
    int off = bsum[blockIdx.x] + excl;
    int run = 0;
#pragma unroll
    for (int j = 0; j < 4; ++j) {
        int i = base + t * 4 + j;
        if (i < N) row_ptr[i] = off + run;
        run += v[j];
    }
}

__global__ void k_fill(const int* __restrict__ src, const int* __restrict__ dst,
                       const int* __restrict__ row_ptr, int* __restrict__ cursor,
                       int* __restrict__ col) {
    int e = blockIdx.x * blockDim.x + threadIdx.x;
    if (e < E) {
        int d = dst[e];
        int p = row_ptr[d] + atomicAdd(&cursor[d], 1);
        col[p] = src[e];
    }
}

__global__ void k_dinv(const int* __restrict__ cs, const int* __restrict__ cd,
                       float* __restrict__ dinv_out, float* __restrict__ dinv_in) {
    int i = blockIdx.x * blockDim.x + threadIdx.x;
    if (i < N) {
        int a = cs[i] > 1 ? cs[i] : 1;
        int b = cd[i] > 1 ? cd[i] : 1;
        dinv_out[i] = rsqrtf((float)a);
        dinv_in[i] = rsqrtf((float)b);
    }
}

__global__ void k_mflag(const int* __restrict__ mask_nodes, int* __restrict__ mflag) {
    int i = blockIdx.x * blockDim.x + threadIdx.x;
    if (i < MASKN) mflag[mask_nodes[i]] = 1;
}

// ---------------- 128x128 transpose: Wt[k][o] = W[o][k] ----------------

__global__ void k_tr(const float* __restrict__ W, float* __restrict__ Wt) {
    __shared__ float tile[32][33];
    int bx = blockIdx.x & 3, by = blockIdx.x >> 2;
    int tx = threadIdx.x & 31, ty8 = threadIdx.x >> 5;
#pragma unroll
    for (int r = ty8; r < 32; r += 8)
        tile[r][tx] = W[(by * 32 + r) * 128 + bx * 32 + tx];
    __syncthreads();
#pragma unroll
    for (int r = ty8; r < 32; r += 8)
        Wt[(bx * 32 + r) * 128 + by * 32 + tx] = tile[tx][r];
}

// ---------------- feature prep: masked x scaled by deg_out^-0.5 ----------------

__global__ void k_prep(const float4* __restrict__ x, const float4* __restrict__ tok,
                       const int* __restrict__ mflag, const float* __restrict__ dinv_out,
                       float4* __restrict__ A) {
    int i = blockIdx.x * blockDim.x + threadIdx.x; // over N*32 float4s
    if (i < N * 32) {
        int row = i >> 5;
        int c = i & 31;
        float s = dinv_out[row];
        float4 v = mflag[row] ? tok[c] : x[i];
        A[i] = make_float4(v.x * s, v.y * s, v.z * s, v.w * s);
    }
}

// ---------------- SpMM: B[row] = sum over CSR neighbors of A[col] ----------------

__global__ void k_spmm(const float4* __restrict__ A4, float4* __restrict__ B4,
                       const int* __restrict__ row_ptr, const int* __restrict__ col,
                       const int* __restrict__ rows, int nrows) {
    int rr = blockIdx.x * blockDim.y + threadIdx.y;
    if (rr >= nrows) return;
    int row = rows ? rows[rr] : rr;
    int lane = threadIdx.x;
    int half = lane >> 5;
    int j = lane & 31;
    int beg = row_ptr[row], end = row_ptr[row + 1];
    float4 acc = make_float4(0.f, 0.f, 0.f, 0.f);
    float4 acc2 = make_float4(0.f, 0.f, 0.f, 0.f);
    int e = beg;
    for (; e + 8 <= end; e += 8) {
        int c0 = col[e + half];
        int c1 = col[e + 2 + half];
        int c2 = col[e + 4 + half];
        int c3 = col[e + 6 + half];
        float4 v0 = A4[(size_t)c0 * 32 + j];
        float4 v1 = A4[(size_t)c1 * 32 + j];
        float4 v2 = A4[(size_t)c2 * 32 + j];
        float4 v3 = A4[(size_t)c3 * 32 + j];
        ADD4(acc, v0);
        ADD4(acc2, v1);
        ADD4(acc, v2);
        ADD4(acc2, v3);
    }
    for (; e + 2 <= end; e += 2) {
        int c = col[e + half];
        float4 v = A4[(size_t)c * 32 + j];
        ADD4(acc, v);
    }
    if (e < end && half == 0) {
        int c = col[e];
        float4 v = A4[(size_t)c * 32 + j];
        ADD4(acc, v);
    }
    ADD4(acc, acc2);
    acc.x += __shfl_xor(acc.x, 32);
    acc.y += __shfl_xor(acc.y, 32);
    acc.z += __shfl_xor(acc.z, 32);
    acc.w += __shfl_xor(acc.w, 32);
    if (half == 0) B4[(size_t)row * 32 + j] = acc;
}

// ---------------- dense GEMM core (named-register accumulators) ----------------
// 256 threads, 32-row tile, 128 cols. tx = t&31 owns cols 4tx..4tx+3,
// ty = t>>5 owns rows ty*4..+3. Row's outputs live in one 32-lane half-wave.
// Wt (pre-transposed, [k][o]) staged to LDS via straight coalesced copy.

// GEMM body as a macro so acc0..acc3 stay NAMED locals (no array -> no scratch).
#define GEMM_CORE(Wt4)                                                         \
    _Pragma("unroll") for (int kh = 0; kh < 2; ++kh) {                         \
        __syncthreads();                                                       \
        _Pragma("unroll") for (int jj = 0; jj < 8; ++jj)                       \
            shw4w[t + 256 * jj] = Wt4[kh * 2048 + t + 256 * jj];               \
        __syncthreads();                                                       \
        _Pragma("unroll") for (int k4 = 0; k4 < 16; ++k4) {                    \
            float4 b0 = shw4[(4 * k4 + 0) * 32 + tx];                          \
            float4 b1 = shw4[(4 * k4 + 1) * 32 + tx];                          \
            float4 b2 = shw4[(4 * k4 + 2) * 32 + tx];                          \
            float4 b3 = shw4[(4 * k4 + 3) * 32 + tx];                          \
            float4 a0 = shi4[(ty * 4 + 0) * 32 + kh * 16 + k4];                \
            float4 a1 = shi4[(ty * 4 + 1) * 32 + kh * 16 + k4];                \
            float4 a2 = shi4[(ty * 4 + 2) * 32 + kh * 16 + k4];                \
            float4 a3 = shi4[(ty * 4 + 3) * 32 + kh * 16 + k4];                \
            FMA4(acc0, a0.x, b0); FMA4(acc0, a0.y, b1);                        \
            FMA4(acc0, a0.z, b2); FMA4(acc0, a0.w, b3);                        \
            FMA4(acc1, a1.x, b0); FMA4(acc1, a1.y, b1);                        \
            FMA4(acc1, a1.z, b2); FMA4(acc1, a1.w, b3);                        \
            FMA4(acc2, a2.x, b0); FMA4(acc2, a2.y, b1);                        \
            FMA4(acc2, a2.z, b2); FMA4(acc2, a2.w, b3);                        \
            FMA4(acc3, a3.x, b0); FMA4(acc3, a3.y, b1);                        \
            FMA4(acc3, a3.z, b2); FMA4(acc3, a3.w, b3);                        \
        }                                                                      \
    }

__device__ __forceinline__ float4 ln_epilogue(float4 v, float di, float4 bb,
                                              float4 gg, float4 ee, float alpha) {
    v.x = (v.x + bb.x) * di;
    v.y = (v.y + bb.y) * di;
    v.z = (v.z + bb.z) * di;
    v.w = (v.w + bb.w) * di;
    float s = v.x + v.y + v.z + v.w;
    float q = v.x * v.x + v.y * v.y + v.z * v.z + v.w * v.w;
#pragma unroll
    for (int o = 16; o > 0; o >>= 1) {
        s += __shfl_xor(s, o);
        q += __shfl_xor(q, o);
    }
    float mu = s * (1.f / D);
    float var = q * (1.f / D) - mu * mu;
    float rs = rsqrtf(var + 1e-5f);
    v.x = (v.x - mu) * rs * gg.x + ee.x;
    v.y = (v.y - mu) * rs * gg.y + ee.y;
    v.z = (v.z - mu) * rs * gg.z + ee.z;
    v.w = (v.w - mu) * rs * gg.w + ee.w;
    v.x = v.x >= 0.f ? v.x : alpha * v.x;
    v.y = v.y >= 0.f ? v.y : alpha * v.y;
    v.z = v.z >= 0.f ? v.z : alpha * v.z;
    v.w = v.w >= 0.f ? v.w : alpha * v.w;
    return v;
}

template <bool LN, bool SCALE_OUT, bool MASK_ZERO>
__launch_bounds__(256, 3) __global__
void k_dense(const float4* __restrict__ in, float4* __restrict__ out,
             const float4* __restrict__ Wt4, const float4* __restrict__ bias4,
             const float4* __restrict__ g4, const float4* __restrict__ be4,
             const float* __restrict__ aP, const float* __restrict__ dinv_in,
             const float* __restrict__ dinv_out, const int* __restrict__ mflag) {
    __shared__ float sh_in[32 * 128];
    __shared__ float sh_w[64 * 128];
    int t = threadIdx.x;
    int tx = t & 31, ty = t >> 5;
    int rbase = blockIdx.x * 32;
    {
        const float4* inb = in + (size_t)rbase * 32;
        float4* s4 = (float4*)sh_in;
        int maxf = (N - rbase) * 32;
#pragma unroll
        for (int jj = 0; jj < 4; ++jj) {
            int f = t + 256 * jj;
            s4[f] = inb[f < maxf ? f : 0];
        }
    }
    float4 acc0 = make_float4(0.f, 0.f, 0.f, 0.f);
    float4 acc1 = acc0, acc2 = acc0, acc3 = acc0;
    float4* shw4w = (float4*)sh_w;
    const float4* shw4 = (const float4*)sh_w;
    const float4* shi4 = (const float4*)sh_in;
    GEMM_CORE(Wt4)

    float alpha = 0.f;
    float4 bb = make_float4(0.f, 0.f, 0.f, 0.f), gg = bb, ee = bb;
    if constexpr (LN) {
        alpha = aP[0];
        bb = bias4[tx];
        gg = g4[tx];
        ee = be4[tx];
    }
#define DENSE_EPI(accR, rr)                                                    \
    {                                                                          \
        int row = rbase + ty * 4 + rr;                                         \
        if (row < N) {                                                         \
            float4 v = accR;                                                   \
            if constexpr (LN) v = ln_epilogue(v, dinv_in[row], bb, gg, ee, alpha); \
            if (MASK_ZERO && mflag[row]) v = make_float4(0.f, 0.f, 0.f, 0.f);  \
            if constexpr (SCALE_OUT) {                                         \
                float so = dinv_out[row];                                      \
                v.x *= so; v.y *= so; v.z *= so; v.w *= so;                    \
            }                                                                  \
            out[(size_t)row * 32 + tx] = v;                                    \
        }                                                                      \
    }
    DENSE_EPI(acc0, 0)
    DENSE_EPI(acc1, 1)
    DENSE_EPI(acc2, 2)
    DENSE_EPI(acc3, 3)
#undef DENSE_EPI
}

// decoder fc + degnorm + SCE loss over masked rows (same GEMM core)
__launch_bounds__(256, 3) __global__
void k_loss(const float4* __restrict__ agg4, const float4* __restrict__ x4,
            const float4* __restrict__ Wt4, const float4* __restrict__ bd4,
            const float* __restrict__ dinv_in, const int* __restrict__ mask_nodes,
            float* __restrict__ outp) {
    __shared__ float sh_in[32 * 128];
    __shared__ float sh_w[64 * 128];
    __shared__ int sh_rows[32];
    __shared__ float sh_acc;
    int t = threadIdx.x;
    int tx = t & 31, ty = t >> 5;
    int base = blockIdx.x * 32;
    if (t < 32) {
        int idx = base + t;
        sh_rows[t] = idx < MASKN ? mask_nodes[idx] : -1;
    }
    if (t == 0) sh_acc = 0.f;
    __syncthreads();
    {
        float4* s4 = (float4*)sh_in;
#pragma unroll
        for (int jj = 0; jj < 4; ++jj) {
            int f = t + 256 * jj;
            int rl = f >> 5, kq = f & 31;
            int m = sh_rows[rl];
            s4[f] = (m >= 0) ? agg4[(size_t)m * 32 + kq]
                             : make_float4(0.f, 0.f, 0.f, 0.f);
        }
    }
    float4 acc0 = make_float4(0.f, 0.f, 0.f, 0.f);
    float4 acc1 = acc0, acc2 = acc0, acc3 = acc0;
    float4* shw4w = (float4*)sh_w;
    const float4* shw4 = (const float4*)sh_w;
    const float4* shi4 = (const float4*)sh_in;
    GEMM_CORE(Wt4)

    float4 bb = bd4[tx];
    float lsum = 0.f;
#define LOSS_EPI(accR, rr)                                                     \
    {                                                                          \
        int m = sh_rows[ty * 4 + rr];                                          \
        if (m >= 0) {                                                          \
            float di = dinv_in[m];                                             \
            float4 r;                                                          \
            r.x = (accR.x + bb.x) * di;                                        \
            r.y = (accR.y + bb.y) * di;                                        \
            r.z = (accR.z + bb.z) * di;                                        \
            r.w = (accR.w + bb.w) * di;                                        \
            float4 xv = x4[(size_t)m * 32 + tx];                               \
            float a = r.x * r.x + r.y * r.y + r.z * r.z + r.w * r.w;           \
            float b = xv.x * xv.x + xv.y * xv.y + xv.z * xv.z + xv.w * xv.w;   \
            float c = r.x * xv.x + r.y * xv.y + r.z * xv.z + r.w * xv.w;       \
            _Pragma("unroll") for (int o = 16; o > 0; o >>= 1) {               \
                a += __shfl_xor(a, o);                                         \
                b += __shfl_xor(b, o);                                         \
                c += __shfl_xor(c, o);                                         \
            }                                                                  \
            if (tx == 0) {                                                     \
                float nr = fmaxf(sqrtf(a), 1e-12f);                            \
                float nx = fmaxf(sqrtf(b), 1e-12f);                            \
                float term = 1.f - c / (nr * nx);                              \
                lsum += term * term;                                           \
            }                                                                  \
        }                                                                      \
    }
    LOSS_EPI(acc0, 0)
    LOSS_EPI(acc1, 1)
    LOSS_EPI(acc2, 2)
    LOSS_EPI(acc3, 3)
#undef LOSS_EPI
    if (tx == 0 && lsum != 0.f) atomicAdd(&sh_acc, lsum);
    __syncthreads();
    if (t == 0) atomicAdd(outp, sh_acc * (1.f / MASKN));
}

// ---------------- launch ----------------

extern "C" void kernel_launch(void* const* d_in, const int* in_sizes, int n_in,
                              void* d_out, int out_size, void* d_ws, size_t ws_size,
                              hipStream_t stream) {
    const float* x = (const float*)d_in[0];
    const float* tok = (const float*)d_in[1];
    const float* W1 = (const float*)d_in[2];
    const float* b1 = (const float*)d_in[3];
    const float* g1 = (const float*)d_in[4];
    const float* be1 = (const float*)d_in[5];
    const float* a1 = (const float*)d_in[6];
    const float* W2 = (const float*)d_in[7];
    const float* b2 = (const float*)d_in[8];
    const float* g2 = (const float*)d_in[9];
    const float* be2 = (const float*)d_in[10];
    const float* a2 = (const float*)d_in[11];
    const float* We2d = (const float*)d_in[12];
    const float* Wd = (const float*)d_in[13];
    const float* bd = (const float*)d_in[14];
    const int* src = (const int*)d_in[15];
    const int* dst = (const int*)d_in[16];
    const int* mask_nodes = (const int*)d_in[17];

    char* w = (char*)d_ws;
    float* A = (float*)w;       w += (size_t)N * D * 4;
    float* Bf = (float*)w;      w += (size_t)N * D * 4;
    int* col = (int*)w;         w += (size_t)E * 4;
    int* row_ptr = (int*)w;     w += (size_t)(N + 1) * 4;
    int* cnt_src = (int*)w;     w += (size_t)N * 4;
    int* cnt_dst = (int*)w;     w += (size_t)N * 4;
    int* cursor = (int*)w;      w += (size_t)N * 4;
    int* mflag = (int*)w;       w += (size_t)N * 4;
    int* bsum = (int*)w;        w += 256 * 4;
    float* dinv_out = (float*)w; w += (size_t)N * 4;
    float* dinv_in = (float*)w;  w += (size_t)N * 4;
    float* Wt1 = (float*)w;     w += (size_t)D * D * 4;
    float* Wt2 = (float*)w;     w += (size_t)D * D * 4;
    float* WtE = (float*)w;     w += (size_t)D * D * 4;
    float* WtD = (float*)w;     w += (size_t)D * D * 4;

    // zero: cnt_src, cnt_dst, cursor, mflag (contiguous 4*N ints) + output scalar
    hipMemsetAsync(cnt_src, 0, (size_t)4 * N * 4, stream);
    hipMemsetAsync(d_out, 0, sizeof(float), stream);

    k_count<<<(E + 255) / 256, 256, 0, stream>>>(src, dst, cnt_src, cnt_dst);
    k_scan1<<<NB_SCAN, 256, 0, stream>>>(cnt_dst, bsum);
    k_scan2<<<1, 64, 0, stream>>>(bsum, row_ptr);
    k_scan3<<<NB_SCAN, 256, 0, stream>>>(cnt_dst, bsum, row_ptr);
    k_fill<<<(E + 255) / 256, 256, 0, stream>>>(src, dst, row_ptr, cursor, col);
    k_dinv<<<(N + 255) / 256, 256, 0, stream>>>(cnt_src, cnt_dst, dinv_out, dinv_in);
    k_mflag<<<(MASKN + 255) / 256, 256, 0, stream>>>(mask_nodes, mflag);
    k_tr<<<16, 256, 0, stream>>>(W1, Wt1);
    k_tr<<<16, 256, 0, stream>>>(W2, Wt2);
    k_tr<<<16, 256, 0, stream>>>(We2d, WtE);
    k_tr<<<16, 256, 0, stream>>>(Wd, WtD);
    k_prep<<<(N * 32 + 255) / 256, 256, 0, stream>>>((const float4*)x, (const float4*)tok,
                                                     mflag, dinv_out, (float4*)A);
    dim3 bs(64, 4);
    int ndense = (N + 31) / 32;
    int nloss = (MASKN + 31) / 32;
    // conv1: agg
    k_spmm<<<(N + 3) / 4, bs, 0, stream>>>((const float4*)A, (float4*)Bf, row_ptr, col, nullptr, N);
    // conv1 epilogue: fc + in-deg norm + LN + PReLU, pre-scale by deg_out^-0.5
    k_dense<true, true, false><<<ndense, 256, 0, stream>>>(
        (const float4*)Bf, (float4*)A, (const float4*)Wt1, (const float4*)b1,
        (const float4*)g1, (const float4*)be1, a1, dinv_in, dinv_out, nullptr);
    // conv2: agg
    k_spmm<<<(N + 3) / 4, bs, 0, stream>>>((const float4*)A, (float4*)Bf, row_ptr, col, nullptr, N);
    // conv2 epilogue: h2 (unscaled)
    k_dense<true, false, false><<<ndense, 256, 0, stream>>>(
        (const float4*)Bf, (float4*)A, (const float4*)Wt2, (const float4*)b2,
        (const float4*)g2, (const float4*)be2, a2, dinv_in, dinv_out, nullptr);
    // encoder_to_decoder + re-mask + pre-scale for conv3
    k_dense<false, true, true><<<ndense, 256, 0, stream>>>(
        (const float4*)A, (float4*)Bf, (const float4*)WtE, nullptr, nullptr,
        nullptr, nullptr, dinv_in, dinv_out, mflag);
    // conv3: agg, masked rows only
    k_spmm<<<(MASKN + 3) / 4, bs, 0, stream>>>((const float4*)Bf, (float4*)A, row_ptr, col,
                                               mask_nodes, MASKN);
    // decoder fc + SCE loss
    k_loss<<<nloss, 256, 0, stream>>>((const float4*)A, (const float4*)x,
                                      (const float4*)WtD, (const float4*)bd,
                                      dinv_in, mask_nodes, (float*)d_out);
}

// Round 4
// 762.876 us; speedup vs baseline: 5.8243x; 5.8243x over previous
//
#include <hip/hip_runtime.h>

constexpr int N = 50000;
constexpr int E = 800000;
constexpr int D = 128;
constexpr int MASKN = 25000;
constexpr int SCAN_CHUNK = 1024;
constexpr int NB_SCAN = (N + SCAN_CHUNK - 1) / SCAN_CHUNK; // 49

#define ADD4(acc, v)                                                           \
    acc.x += v.x;                                                              \
    acc.y += v.y;                                                              \
    acc.z += v.z;                                                              \
    acc.w += v.w

// ---------------- CSR build ----------------

__global__ void k_count(const int* __restrict__ src, const int* __restrict__ dst,
                        int* __restrict__ cnt_src, int* __restrict__ cnt_dst) {
    int e = blockIdx.x * blockDim.x + threadIdx.x;
    if (e < E) {
        atomicAdd(&cnt_src[src[e]], 1);
        atomicAdd(&cnt_dst[dst[e]], 1);
    }
}

__global__ void k_scan1(const int* __restrict__ cnt, int* __restrict__ bsum) {
    __shared__ int sh[256];
    int base = blockIdx.x * SCAN_CHUNK;
    int t = threadIdx.x;
    int s = 0;
#pragma unroll
    for (int j = 0; j < 4; ++j) {
        int i = base + t * 4 + j;
        if (i < N) s += cnt[i];
    }
    sh[t] = s;
    __syncthreads();
    for (int o = 128; o > 0; o >>= 1) {
        if (t < o) sh[t] += sh[t + o];
        __syncthreads();
    }
    if (t == 0) bsum[blockIdx.x] = sh[0];
}

__global__ void k_scan2(int* __restrict__ bsum, int* __restrict__ row_ptr) {
    if (threadIdx.x == 0 && blockIdx.x == 0) {
        int run = 0;
        for (int i = 0; i < NB_SCAN; ++i) {
            int v = bsum[i];
            bsum[i] = run;
            run += v;
        }
        row_ptr[N] = run; // == E
    }
}

__global__ void k_scan3(const int* __restrict__ cnt, const int* __restrict__ bsum,
                        int* __restrict__ row_ptr) {
    __shared__ int sh[256];
    int base = blockIdx.x * SCAN_CHUNK;
    int t = threadIdx.x;
    int v[4];
    int tot = 0;
#pragma unroll
    for (int j = 0; j < 4; ++j) {
        int i = base + t * 4 + j;
        v[j] = (i < N) ? cnt[i] : 0;
        tot += v[j];
    }
    sh[t] = tot;
    __syncthreads();
    for (int o = 1; o < 256; o <<= 1) {
        int y = (t >= o) ? sh[t - o] : 0;
        __syncthreads();
        sh[t] += y;
        __syncthreads();
    }
    int excl = sh[t] - tot;
    int off = bsum[blockIdx.x] + excl;
    int run = 0;
#pragma unroll
    for (int j = 0; j < 4; ++j) {
        int i = base + t * 4 + j;
        if (i < N) row_ptr[i] = off + run;
        run += v[j];
    }
}

__global__ void k_fill(const int* __restrict__ src, const int* __restrict__ dst,
                       const int* __restrict__ row_ptr, int* __restrict__ cursor,
                       int* __restrict__ col) {
    int e = blockIdx.x * blockDim.x + threadIdx.x;
    if (e < E) {
        int d = dst[e];
        int p = row_ptr[d] + atomicAdd(&cursor[d], 1);
        col[p] = src[e];
    }
}

__global__ void k_dinv(const int* __restrict__ cs, const int* __restrict__ cd,
                       float* __restrict__ dinv_out, float* __restrict__ dinv_in) {
    int i = blockIdx.x * blockDim.x + threadIdx.x;
    if (i < N) {
        int a = cs[i] > 1 ? cs[i] : 1;
        int b = cd[i] > 1 ? cd[i] : 1;
        dinv_out[i] = rsqrtf((float)a);
        dinv_in[i] = rsqrtf((float)b);
    }
}

__global__ void k_mflag(const int* __restrict__ mask_nodes, int* __restrict__ mflag) {
    int i = blockIdx.x * blockDim.x + threadIdx.x;
    if (i < MASKN) mflag[mask_nodes[i]] = 1;
}

// ---------------- feature prep: masked x scaled by deg_out^-0.5 ----------------

__global__ void k_prep(const float4* __restrict__ x, const float4* __restrict__ tok,
                       const int* __restrict__ mflag, const float* __restrict__ dinv_out,
                       float4* __restrict__ A) {
    int i = blockIdx.x * blockDim.x + threadIdx.x; // over N*32 float4s
    if (i < N * 32) {
        int row = i >> 5;
        int c = i & 31;
        float s = dinv_out[row];
        float4 v = mflag[row] ? tok[c] : x[i];
        A[i] = make_float4(v.x * s, v.y * s, v.z * s, v.w * s);
    }
}

// ---------------- SpMM: B[row] = sum over CSR neighbors of A[col] ----------------

__global__ void k_spmm(const float4* __restrict__ A4, float4* __restrict__ B4,
                       const int* __restrict__ row_ptr, const int* __restrict__ col,
                       const int* __restrict__ rows, int nrows) {
    int rr = blockIdx.x * blockDim.y + threadIdx.y;
    if (rr >= nrows) return;
    int row = rows ? rows[rr] : rr;
    int lane = threadIdx.x;
    int half = lane >> 5;
    int j = lane & 31;
    int beg = row_ptr[row], end = row_ptr[row + 1];
    float4 acc = make_float4(0.f, 0.f, 0.f, 0.f);
    float4 acc2 = make_float4(0.f, 0.f, 0.f, 0.f);
    int e = beg;
    for (; e + 8 <= end; e += 8) {
        int c0 = col[e + half];
        int c1 = col[e + 2 + half];
        int c2 = col[e + 4 + half];
        int c3 = col[e + 6 + half];
        float4 v0 = A4[(size_t)c0 * 32 + j];
        float4 v1 = A4[(size_t)c1 * 32 + j];
        float4 v2 = A4[(size_t)c2 * 32 + j];
        float4 v3 = A4[(size_t)c3 * 32 + j];
        ADD4(acc, v0);
        ADD4(acc2, v1);
        ADD4(acc, v2);
        ADD4(acc2, v3);
    }
    for (; e + 2 <= end; e += 2) {
        int c = col[e + half];
        float4 v = A4[(size_t)c * 32 + j];
        ADD4(acc, v);
    }
    if (e < end && half == 0) {
        int c = col[e];
        float4 v = A4[(size_t)c * 32 + j];
        ADD4(acc, v);
    }
    ADD4(acc, acc2);
    acc.x += __shfl_xor(acc.x, 32);
    acc.y += __shfl_xor(acc.y, 32);
    acc.z += __shfl_xor(acc.z, 32);
    acc.w += __shfl_xor(acc.w, 32);
    if (half == 0) B4[(size_t)row * 32 + j] = acc;
}

// ---------------- dense: thread t = output col, 4 rows per block ----------------
// W read directly from global (row t contiguous per thread, L1/L2-hot);
// input rows broadcast from LDS. Proven-clean R1 structure + 4-row amortization.

#define DOT_STEP(w, a, acc)                                                    \
    acc = fmaf(w.x, a.x, acc);                                                 \
    acc = fmaf(w.y, a.y, acc);                                                 \
    acc = fmaf(w.z, a.z, acc);                                                 \
    acc = fmaf(w.w, a.w, acc)

template <bool LN, bool SCALE_OUT, bool MASK_ZERO>
__launch_bounds__(128)
__global__ void k_dense(const float* __restrict__ in, float* __restrict__ out,
                        const float* __restrict__ W, const float* __restrict__ bias,
                        const float* __restrict__ g, const float* __restrict__ be,
                        const float* __restrict__ aP, const float* __restrict__ dinv_in,
                        const float* __restrict__ dinv_out, const int* __restrict__ mflag) {
    __shared__ float sh[4 * 128];
    __shared__ float red[16];
    int t = threadIdx.x;
    int r0 = blockIdx.x * 4; // N % 4 == 0, no guard
#pragma unroll
    for (int i = 0; i < 4; ++i) sh[i * 128 + t] = in[(size_t)(r0 + i) * 128 + t];
    __syncthreads();
    const float4* Wrow = (const float4*)(W + (size_t)t * 128);
    const float4* sh4 = (const float4*)sh;
    float acc0 = 0.f, acc1 = 0.f, acc2 = 0.f, acc3 = 0.f;
#pragma unroll 4
    for (int k4 = 0; k4 < 32; ++k4) {
        float4 w = Wrow[k4];
        float4 a0 = sh4[0 * 32 + k4];
        float4 a1 = sh4[1 * 32 + k4];
        float4 a2 = sh4[2 * 32 + k4];
        float4 a3 = sh4[3 * 32 + k4];
        DOT_STEP(w, a0, acc0);
        DOT_STEP(w, a1, acc1);
        DOT_STEP(w, a2, acc2);
        DOT_STEP(w, a3, acc3);
    }
    float v0 = acc0, v1 = acc1, v2 = acc2, v3 = acc3;
    if constexpr (LN) {
        float bt = bias[t];
        float di0 = dinv_in[r0], di1 = dinv_in[r0 + 1];
        float di2 = dinv_in[r0 + 2], di3 = dinv_in[r0 + 3];
        v0 = (v0 + bt) * di0;
        v1 = (v1 + bt) * di1;
        v2 = (v2 + bt) * di2;
        v3 = (v3 + bt) * di3;
        float s0 = v0, s1 = v1, s2 = v2, s3 = v3;
        float q0 = v0 * v0, q1 = v1 * v1, q2 = v2 * v2, q3 = v3 * v3;
#pragma unroll
        for (int o = 32; o > 0; o >>= 1) {
            s0 += __shfl_xor(s0, o);
            q0 += __shfl_xor(q0, o);
            s1 += __shfl_xor(s1, o);
            q1 += __shfl_xor(q1, o);
            s2 += __shfl_xor(s2, o);
            q2 += __shfl_xor(q2, o);
            s3 += __shfl_xor(s3, o);
            q3 += __shfl_xor(q3, o);
        }
        if ((t & 63) == 0) {
            int wv = t >> 6;
            red[wv * 8 + 0] = s0;
            red[wv * 8 + 1] = q0;
            red[wv * 8 + 2] = s1;
            red[wv * 8 + 3] = q1;
            red[wv * 8 + 4] = s2;
            red[wv * 8 + 5] = q2;
            red[wv * 8 + 6] = s3;
            red[wv * 8 + 7] = q3;
        }
        __syncthreads();
        float gt = g[t], bet = be[t], alpha = aP[0];
#define LN_ROW(vi, si_idx)                                                     \
    {                                                                          \
        float S = red[si_idx] + red[8 + si_idx];                               \
        float Q = red[si_idx + 1] + red[8 + si_idx + 1];                       \
        float mu = S * (1.f / D);                                              \
        float var = Q * (1.f / D) - mu * mu;                                   \
        float rs = rsqrtf(var + 1e-5f);                                        \
        vi = (vi - mu) * rs * gt + bet;                                        \
        vi = vi >= 0.f ? vi : alpha * vi;                                      \
    }
        LN_ROW(v0, 0)
        LN_ROW(v1, 2)
        LN_ROW(v2, 4)
        LN_ROW(v3, 6)
#undef LN_ROW
    }
    if constexpr (MASK_ZERO) {
        if (mflag[r0]) v0 = 0.f;
        if (mflag[r0 + 1]) v1 = 0.f;
        if (mflag[r0 + 2]) v2 = 0.f;
        if (mflag[r0 + 3]) v3 = 0.f;
    }
    if constexpr (SCALE_OUT) {
        v0 *= dinv_out[r0];
        v1 *= dinv_out[r0 + 1];
        v2 *= dinv_out[r0 + 2];
        v3 *= dinv_out[r0 + 3];
    }
    out[(size_t)r0 * 128 + t] = v0;
    out[(size_t)(r0 + 1) * 128 + t] = v1;
    out[(size_t)(r0 + 2) * 128 + t] = v2;
    out[(size_t)(r0 + 3) * 128 + t] = v3;
}

// decoder fc + degnorm + SCE loss over masked rows, same structure
__launch_bounds__(128)
__global__ void k_loss(const float* __restrict__ agg, const float* __restrict__ x,
                       const float* __restrict__ Wd, const float* __restrict__ bd,
                       const float* __restrict__ dinv_in, const int* __restrict__ mask_nodes,
                       float* __restrict__ outp) {
    __shared__ float sh[4 * 128];
    __shared__ float red[24];
    int t = threadIdx.x;
    int i0 = blockIdx.x * 4; // MASKN % 4 == 0
    int m0 = mask_nodes[i0], m1 = mask_nodes[i0 + 1];
    int m2 = mask_nodes[i0 + 2], m3 = mask_nodes[i0 + 3];
    sh[0 * 128 + t] = agg[(size_t)m0 * 128 + t];
    sh[1 * 128 + t] = agg[(size_t)m1 * 128 + t];
    sh[2 * 128 + t] = agg[(size_t)m2 * 128 + t];
    sh[3 * 128 + t] = agg[(size_t)m3 * 128 + t];
    __syncthreads();
    const float4* Wrow = (const float4*)(Wd + (size_t)t * 128);
    const float4* sh4 = (const float4*)sh;
    float acc0 = 0.f, acc1 = 0.f, acc2 = 0.f, acc3 = 0.f;
#pragma unroll 4
    for (int k4 = 0; k4 < 32; ++k4) {
        float4 w = Wrow[k4];
        float4 a0 = sh4[0 * 32 + k4];
        float4 a1 = sh4[1 * 32 + k4];
        float4 a2 = sh4[2 * 32 + k4];
        float4 a3 = sh4[3 * 32 + k4];
        DOT_STEP(w, a0, acc0);
        DOT_STEP(w, a1, acc1);
        DOT_STEP(w, a2, acc2);
        DOT_STEP(w, a3, acc3);
    }
    float bt = bd[t];
    float r_0 = (acc0 + bt) * dinv_in[m0];
    float r_1 = (acc1 + bt) * dinv_in[m1];
    float r_2 = (acc2 + bt) * dinv_in[m2];
    float r_3 = (acc3 + bt) * dinv_in[m3];
    float x0 = x[(size_t)m0 * 128 + t];
    float x1 = x[(size_t)m1 * 128 + t];
    float x2 = x[(size_t)m2 * 128 + t];
    float x3 = x[(size_t)m3 * 128 + t];
    float a0 = r_0 * r_0, b0 = x0 * x0, c0 = r_0 * x0;
    float a1 = r_1 * r_1, b1 = x1 * x1, c1 = r_1 * x1;
    float a2 = r_2 * r_2, b2 = x2 * x2, c2 = r_2 * x2;
    float a3 = r_3 * r_3, b3 = x3 * x3, c3 = r_3 * x3;
#pragma unroll
    for (int o = 32; o > 0; o >>= 1) {
        a0 += __shfl_xor(a0, o); b0 += __shfl_xor(b0, o); c0 += __shfl_xor(c0, o);
        a1 += __shfl_xor(a1, o); b1 += __shfl_xor(b1, o); c1 += __shfl_xor(c1, o);
        a2 += __shfl_xor(a2, o); b2 += __shfl_xor(b2, o); c2 += __shfl_xor(c2, o);
        a3 += __shfl_xor(a3, o); b3 += __shfl_xor(b3, o); c3 += __shfl_xor(c3, o);
    }
    if ((t & 63) == 0) {
        int wv = t >> 6;
        red[wv * 12 + 0] = a0; red[wv * 12 + 1] = b0; red[wv * 12 + 2] = c0;
        red[wv * 12 + 3] = a1; red[wv * 12 + 4] = b1; red[wv * 12 + 5] = c1;
        red[wv * 12 + 6] = a2; red[wv * 12 + 7] = b2; red[wv * 12 + 8] = c2;
        red[wv * 12 + 9] = a3; red[wv * 12 + 10] = b3; red[wv * 12 + 11] = c3;
    }
    __syncthreads();
    if (t == 0) {
        float sum = 0.f;
#pragma unroll
        for (int i = 0; i < 4; ++i) {
            float A_ = red[i * 3 + 0] + red[12 + i * 3 + 0];
            float B_ = red[i * 3 + 1] + red[12 + i * 3 + 1];
            float C_ = red[i * 3 + 2] + red[12 + i * 3 + 2];
            float nr = fmaxf(sqrtf(A_), 1e-12f);
            float nx = fmaxf(sqrtf(B_), 1e-12f);
            float term = 1.f - C_ / (nr * nx);
            sum += term * term;
        }
        atomicAdd(outp, sum * (1.f / MASKN));
    }
}

// ---------------- launch ----------------

extern "C" void kernel_launch(void* const* d_in, const int* in_sizes, int n_in,
                              void* d_out, int out_size, void* d_ws, size_t ws_size,
                              hipStream_t stream) {
    const float* x = (const float*)d_in[0];
    const float* tok = (const float*)d_in[1];
    const float* W1 = (const float*)d_in[2];
    const float* b1 = (const float*)d_in[3];
    const float* g1 = (const float*)d_in[4];
    const float* be1 = (const float*)d_in[5];
    const float* a1 = (const float*)d_in[6];
    const float* W2 = (const float*)d_in[7];
    const float* b2 = (const float*)d_in[8];
    const float* g2 = (const float*)d_in[9];
    const float* be2 = (const float*)d_in[10];
    const float* a2 = (const float*)d_in[11];
    const float* We2d = (const float*)d_in[12];
    const float* Wd = (const float*)d_in[13];
    const float* bd = (const float*)d_in[14];
    const int* src = (const int*)d_in[15];
    const int* dst = (const int*)d_in[16];
    const int* mask_nodes = (const int*)d_in[17];

    char* w = (char*)d_ws;
    float* A = (float*)w;       w += (size_t)N * D * 4;
    float* Bf = (float*)w;      w += (size_t)N * D * 4;
    int* col = (int*)w;         w += (size_t)E * 4;
    int* row_ptr = (int*)w;     w += (size_t)(N + 1) * 4;
    int* cnt_src = (int*)w;     w += (size_t)N * 4;
    int* cnt_dst = (int*)w;     w += (size_t)N * 4;
    int* cursor = (int*)w;      w += (size_t)N * 4;
    int* mflag = (int*)w;       w += (size_t)N * 4;
    int* bsum = (int*)w;        w += 256 * 4;
    float* dinv_out = (float*)w; w += (size_t)N * 4;
    float* dinv_in = (float*)w;  w += (size_t)N * 4;

    // zero: cnt_src, cnt_dst, cursor, mflag (contiguous 4*N ints) + output scalar
    hipMemsetAsync(cnt_src, 0, (size_t)4 * N * 4, stream);
    hipMemsetAsync(d_out, 0, sizeof(float), stream);

    k_count<<<(E + 255) / 256, 256, 0, stream>>>(src, dst, cnt_src, cnt_dst);
    k_scan1<<<NB_SCAN, 256, 0, stream>>>(cnt_dst, bsum);
    k_scan2<<<1, 64, 0, stream>>>(bsum, row_ptr);
    k_scan3<<<NB_SCAN, 256, 0, stream>>>(cnt_dst, bsum, row_ptr);
    k_fill<<<(E + 255) / 256, 256, 0, stream>>>(src, dst, row_ptr, cursor, col);
    k_dinv<<<(N + 255) / 256, 256, 0, stream>>>(cnt_src, cnt_dst, dinv_out, dinv_in);
    k_mflag<<<(MASKN + 255) / 256, 256, 0, stream>>>(mask_nodes, mflag);
    k_prep<<<(N * 32 + 255) / 256, 256, 0, stream>>>((const float4*)x, (const float4*)tok,
                                                     mflag, dinv_out, (float4*)A);
    dim3 bs(64, 4);
    int ndense = N / 4;     // 12500
    int nloss = MASKN / 4;  // 6250
    // conv1: agg
    k_spmm<<<(N + 3) / 4, bs, 0, stream>>>((const float4*)A, (float4*)Bf, row_ptr, col, nullptr, N);
    // conv1 epilogue: fc + in-deg norm + LN + PReLU, pre-scale by deg_out^-0.5
    k_dense<true, true, false><<<ndense, 128, 0, stream>>>(
        Bf, A, W1, b1, g1, be1, a1, dinv_in, dinv_out, nullptr);
    // conv2: agg
    k_spmm<<<(N + 3) / 4, bs, 0, stream>>>((const float4*)A, (float4*)Bf, row_ptr, col, nullptr, N);
    // conv2 epilogue: h2 (unscaled)
    k_dense<true, false, false><<<ndense, 128, 0, stream>>>(
        Bf, A, W2, b2, g2, be2, a2, dinv_in, dinv_out, nullptr);
    // encoder_to_decoder + re-mask + pre-scale for conv3
    k_dense<false, true, true><<<ndense, 128, 0, stream>>>(
        A, Bf, We2d, nullptr, nullptr, nullptr, nullptr, dinv_in, dinv_out, mflag);
    // conv3: agg, masked rows only
    k_spmm<<<(MASKN + 3) / 4, bs, 0, stream>>>((const float4*)Bf, (float4*)A, row_ptr, col,
                                               mask_nodes, MASKN);
    // decoder fc + SCE loss
    k_loss<<<nloss, 128, 0, stream>>>(A, x, Wd, bd, dinv_in, mask_nodes, (float*)d_out);
}

// Round 5
// 556.611 us; speedup vs baseline: 7.9826x; 1.3706x over previous
//
#include <hip/hip_runtime.h>

constexpr int N = 50000;
constexpr int E = 800000;
constexpr int D = 128;
constexpr int MASKN = 25000;
constexpr int SCAN_CHUNK = 1024;
constexpr int NB_SCAN = (N + SCAN_CHUNK - 1) / SCAN_CHUNK; // 49

#define ADD4(acc, v)                                                           \
    acc.x += v.x;                                                              \
    acc.y += v.y;                                                              \
    acc.z += v.z;                                                              \
    acc.w += v.w

#define DOT_STEP(w, a, acc)                                                    \
    acc = fmaf(w.x, a.x, acc);                                                 \
    acc = fmaf(w.y, a.y, acc);                                                 \
    acc = fmaf(w.z, a.z, acc);                                                 \
    acc = fmaf(w.w, a.w, acc)

#define ROW8(X) X(0) X(1) X(2) X(3) X(4) X(5) X(6) X(7)

// ---------------- CSR build ----------------

__global__ void k_count(const int* __restrict__ src, const int* __restrict__ dst,
                        int* __restrict__ cnt_src, int* __restrict__ cnt_dst) {
    int e = blockIdx.x * blockDim.x + threadIdx.x;
    if (e < E) {
        atomicAdd(&cnt_src[src[e]], 1);
        atomicAdd(&cnt_dst[dst[e]], 1);
    }
}

__global__ void k_scan1(const int* __restrict__ cnt, int* __restrict__ bsum) {
    __shared__ int sh[256];
    int base = blockIdx.x * SCAN_CHUNK;
    int t = threadIdx.x;
    int s = 0;
#pragma unroll
    for (int j = 0; j < 4; ++j) {
        int i = base + t * 4 + j;
        if (i < N) s += cnt[i];
    }
    sh[t] = s;
    __syncthreads();
    for (int o = 128; o > 0; o >>= 1) {
        if (t < o) sh[t] += sh[t + o];
        __syncthreads();
    }
    if (t == 0) bsum[blockIdx.x] = sh[0];
}

__global__ void k_scan2(int* __restrict__ bsum, int* __restrict__ row_ptr) {
    if (threadIdx.x == 0 && blockIdx.x == 0) {
        int run = 0;
        for (int i = 0; i < NB_SCAN; ++i) {
            int v = bsum[i];
            bsum[i] = run;
            run += v;
        }
        row_ptr[N] = run; // == E
    }
}

__global__ void k_scan3(const int* __restrict__ cnt, const int* __restrict__ bsum,
                        int* __restrict__ row_ptr) {
    __shared__ int sh[256];
    int base = blockIdx.x * SCAN_CHUNK;
    int t = threadIdx.x;
    int v[4];
    int tot = 0;
#pragma unroll
    for (int j = 0; j < 4; ++j) {
        int i = base + t * 4 + j;
        v[j] = (i < N) ? cnt[i] : 0;
        tot += v[j];
    }
    sh[t] = tot;
    __syncthreads();
    for (int o = 1; o < 256; o <<= 1) {
        int y = (t >= o) ? sh[t - o] : 0;
        __syncthreads();
        sh[t] += y;
        __syncthreads();
    }
    int excl = sh[t] - tot;
    int off = bsum[blockIdx.x] + excl;
    int run = 0;
#pragma unroll
    for (int j = 0; j < 4; ++j) {
        int i = base + t * 4 + j;
        if (i < N) row_ptr[i] = off + run;
        run += v[j];
    }
}

__global__ void k_fill(const int* __restrict__ src, const int* __restrict__ dst,
                       const int* __restrict__ row_ptr, int* __restrict__ cursor,
                       int* __restrict__ col) {
    int e = blockIdx.x * blockDim.x + threadIdx.x;
    if (e < E) {
        int d = dst[e];
        int p = row_ptr[d] + atomicAdd(&cursor[d], 1);
        col[p] = src[e];
    }
}

__global__ void k_dinv(const int* __restrict__ cs, const int* __restrict__ cd,
                       float* __restrict__ dinv_out, float* __restrict__ dinv_in) {
    int i = blockIdx.x * blockDim.x + threadIdx.x;
    if (i < N) {
        int a = cs[i] > 1 ? cs[i] : 1;
        int b = cd[i] > 1 ? cd[i] : 1;
        dinv_out[i] = rsqrtf((float)a);
        dinv_in[i] = rsqrtf((float)b);
    }
}

__global__ void k_mflag(const int* __restrict__ mask_nodes, int* __restrict__ mflag) {
    int i = blockIdx.x * blockDim.x + threadIdx.x;
    if (i < MASKN) mflag[mask_nodes[i]] = 1;
}

// ---------------- W transpose at float4 granularity: Wr4[k4*128+o] = W4[o*32+k4]

__global__ void k_tr4(const float4* __restrict__ W4, float4* __restrict__ Wr4) {
    int idx = blockIdx.x * 256 + threadIdx.x; // 4096 total
    int o = idx >> 5, k4 = idx & 31;
    Wr4[k4 * 128 + o] = W4[idx];
}

// ---------------- feature prep: masked x scaled by deg_out^-0.5 ----------------

__global__ void k_prep(const float4* __restrict__ x, const float4* __restrict__ tok,
                       const int* __restrict__ mflag, const float* __restrict__ dinv_out,
                       float4* __restrict__ A) {
    int i = blockIdx.x * blockDim.x + threadIdx.x; // over N*32 float4s
    if (i < N * 32) {
        int row = i >> 5;
        int c = i & 31;
        float s = dinv_out[row];
        float4 v = mflag[row] ? tok[c] : x[i];
        A[i] = make_float4(v.x * s, v.y * s, v.z * s, v.w * s);
    }
}

// ---------------- SpMM: B[row] = sum over CSR neighbors of A[col] ----------------

__global__ void k_spmm(const float4* __restrict__ A4, float4* __restrict__ B4,
                       const int* __restrict__ row_ptr, const int* __restrict__ col,
                       const int* __restrict__ rows, int nrows) {
    int rr = blockIdx.x * blockDim.y + threadIdx.y;
    if (rr >= nrows) return;
    int row = rows ? rows[rr] : rr;
    int lane = threadIdx.x;
    int half = lane >> 5;
    int j = lane & 31;
    int beg = row_ptr[row], end = row_ptr[row + 1];
    float4 acc = make_float4(0.f, 0.f, 0.f, 0.f);
    float4 acc2 = make_float4(0.f, 0.f, 0.f, 0.f);
    int e = beg;
    for (; e + 8 <= end; e += 8) {
        int c0 = col[e + half];
        int c1 = col[e + 2 + half];
        int c2 = col[e + 4 + half];
        int c3 = col[e + 6 + half];
        float4 v0 = A4[(size_t)c0 * 32 + j];
        float4 v1 = A4[(size_t)c1 * 32 + j];
        float4 v2 = A4[(size_t)c2 * 32 + j];
        float4 v3 = A4[(size_t)c3 * 32 + j];
        ADD4(acc, v0);
        ADD4(acc2, v1);
        ADD4(acc, v2);
        ADD4(acc2, v3);
    }
    for (; e + 2 <= end; e += 2) {
        int c = col[e + half];
        float4 v = A4[(size_t)c * 32 + j];
        ADD4(acc, v);
    }
    if (e < end && half == 0) {
        int c = col[e];
        float4 v = A4[(size_t)c * 32 + j];
        ADD4(acc, v);
    }
    ADD4(acc, acc2);
    acc.x += __shfl_xor(acc.x, 32);
    acc.y += __shfl_xor(acc.y, 32);
    acc.z += __shfl_xor(acc.z, 32);
    acc.w += __shfl_xor(acc.w, 32);
    if (half == 0) B4[(size_t)row * 32 + j] = acc;
}

// ---------------- dense: thread t = output col, 8 rows/block, coalesced Wr ----
// Wr4[k4*128 + t]: lane-consecutive float4 -> one 1KB coalesced load per k4.

template <bool LN, bool SCALE_OUT, bool MASK_ZERO>
__launch_bounds__(128)
__global__ void k_dense(const float* __restrict__ in, float* __restrict__ out,
                        const float4* __restrict__ Wr4, const float* __restrict__ bias,
                        const float* __restrict__ g, const float* __restrict__ be,
                        const float* __restrict__ aP, const float* __restrict__ dinv_in,
                        const float* __restrict__ dinv_out, const int* __restrict__ mflag) {
    __shared__ float sh[8 * 128];
    __shared__ float red[32];
    int t = threadIdx.x;
    int r0 = blockIdx.x * 8; // N % 8 == 0
    {
        const float4* inb = (const float4*)(in + (size_t)r0 * 128);
        float4* s4 = (float4*)sh;
        s4[t] = inb[t];
        s4[t + 128] = inb[t + 128];
    }
    __syncthreads();
    const float4* sh4 = (const float4*)sh;
    float acc0 = 0.f, acc1 = 0.f, acc2 = 0.f, acc3 = 0.f;
    float acc4 = 0.f, acc5 = 0.f, acc6 = 0.f, acc7 = 0.f;
#pragma unroll 2
    for (int k4 = 0; k4 < 32; ++k4) {
        float4 w = Wr4[k4 * 128 + t];
#define DENSE_FMA(i)                                                           \
        {                                                                      \
            float4 a = sh4[i * 32 + k4];                                       \
            DOT_STEP(w, a, acc##i);                                            \
        }
        ROW8(DENSE_FMA)
#undef DENSE_FMA
    }
    float v0 = acc0, v1 = acc1, v2 = acc2, v3 = acc3;
    float v4 = acc4, v5 = acc5, v6 = acc6, v7 = acc7;
    if constexpr (LN) {
        float bt = bias[t];
#define LN_PRE(i) v##i = (v##i + bt) * dinv_in[r0 + i];
        ROW8(LN_PRE)
#undef LN_PRE
#define LN_DECL(i) float s##i = v##i, q##i = v##i * v##i;
        ROW8(LN_DECL)
#undef LN_DECL
#pragma unroll
        for (int o = 32; o > 0; o >>= 1) {
#define LN_SHFL(i)                                                             \
            s##i += __shfl_xor(s##i, o);                                       \
            q##i += __shfl_xor(q##i, o);
            ROW8(LN_SHFL)
#undef LN_SHFL
        }
        if ((t & 63) == 0) {
            int wv = t >> 6;
#define LN_RED(i)                                                              \
            red[wv * 16 + 2 * i] = s##i;                                       \
            red[wv * 16 + 2 * i + 1] = q##i;
            ROW8(LN_RED)
#undef LN_RED
        }
        __syncthreads();
        float gt = g[t], bet = be[t], alpha = aP[0];
#define LN_ROW(i)                                                              \
        {                                                                      \
            float S = red[2 * i] + red[16 + 2 * i];                            \
            float Q = red[2 * i + 1] + red[16 + 2 * i + 1];                    \
            float mu = S * (1.f / D);                                          \
            float var = Q * (1.f / D) - mu * mu;                               \
            float rs = rsqrtf(var + 1e-5f);                                    \
            v##i = (v##i - mu) * rs * gt + bet;                                \
            v##i = v##i >= 0.f ? v##i : alpha * v##i;                          \
        }
        ROW8(LN_ROW)
#undef LN_ROW
    }
    if constexpr (MASK_ZERO) {
#define MZ(i) if (mflag[r0 + i]) v##i = 0.f;
        ROW8(MZ)
#undef MZ
    }
    if constexpr (SCALE_OUT) {
#define SO(i) v##i *= dinv_out[r0 + i];
        ROW8(SO)
#undef SO
    }
#define STORE(i) out[(size_t)(r0 + i) * 128 + t] = v##i;
    ROW8(STORE)
#undef STORE
}

// decoder fc + degnorm + SCE loss over masked rows, same coalesced-W structure
__launch_bounds__(128)
__global__ void k_loss(const float* __restrict__ agg, const float* __restrict__ x,
                       const float4* __restrict__ Wr4, const float* __restrict__ bd,
                       const float* __restrict__ dinv_in, const int* __restrict__ mask_nodes,
                       float* __restrict__ outp) {
    __shared__ float sh[8 * 128];
    __shared__ float red[48];
    __shared__ int shm[8];
    int t = threadIdx.x;
    int i0 = blockIdx.x * 8; // MASKN % 8 == 0
    if (t < 8) shm[t] = mask_nodes[i0 + t];
    __syncthreads();
#pragma unroll
    for (int i = 0; i < 8; ++i) sh[i * 128 + t] = agg[(size_t)shm[i] * 128 + t];
    __syncthreads();
    const float4* sh4 = (const float4*)sh;
    float acc0 = 0.f, acc1 = 0.f, acc2 = 0.f, acc3 = 0.f;
    float acc4 = 0.f, acc5 = 0.f, acc6 = 0.f, acc7 = 0.f;
#pragma unroll 2
    for (int k4 = 0; k4 < 32; ++k4) {
        float4 w = Wr4[k4 * 128 + t];
#define LOSS_FMA(i)                                                            \
        {                                                                      \
            float4 a = sh4[i * 32 + k4];                                       \
            DOT_STEP(w, a, acc##i);                                            \
        }
        ROW8(LOSS_FMA)
#undef LOSS_FMA
    }
    float bt = bd[t];
#define LOSS_RXC(i)                                                            \
    float r##i = (acc##i + bt) * dinv_in[shm[i]];                              \
    float xv##i = x[(size_t)shm[i] * 128 + t];                                 \
    float a##i = r##i * r##i, b##i = xv##i * xv##i, c##i = r##i * xv##i;
    ROW8(LOSS_RXC)
#undef LOSS_RXC
#pragma unroll
    for (int o = 32; o > 0; o >>= 1) {
#define LOSS_SHFL(i)                                                           \
        a##i += __shfl_xor(a##i, o);                                           \
        b##i += __shfl_xor(b##i, o);                                           \
        c##i += __shfl_xor(c##i, o);
        ROW8(LOSS_SHFL)
#undef LOSS_SHFL
    }
    if ((t & 63) == 0) {
        int wv = t >> 6;
#define LOSS_RED(i)                                                            \
        red[wv * 24 + 3 * i] = a##i;                                           \
        red[wv * 24 + 3 * i + 1] = b##i;                                       \
        red[wv * 24 + 3 * i + 2] = c##i;
        ROW8(LOSS_RED)
#undef LOSS_RED
    }
    __syncthreads();
    if (t == 0) {
        float sum = 0.f;
#pragma unroll
        for (int i = 0; i < 8; ++i) {
            float A_ = red[3 * i] + red[24 + 3 * i];
            float B_ = red[3 * i + 1] + red[24 + 3 * i + 1];
            float C_ = red[3 * i + 2] + red[24 + 3 * i + 2];
            float nr = fmaxf(sqrtf(A_), 1e-12f);
            float nx = fmaxf(sqrtf(B_), 1e-12f);
            float term = 1.f - C_ / (nr * nx);
            sum += term * term;
        }
        atomicAdd(outp, sum * (1.f / MASKN));
    }
}

// ---------------- launch ----------------

extern "C" void kernel_launch(void* const* d_in, const int* in_sizes, int n_in,
                              void* d_out, int out_size, void* d_ws, size_t ws_size,
                              hipStream_t stream) {
    const float* x = (const float*)d_in[0];
    const float* tok = (const float*)d_in[1];
    const float* W1 = (const float*)d_in[2];
    const float* b1 = (const float*)d_in[3];
    const float* g1 = (const float*)d_in[4];
    const float* be1 = (const float*)d_in[5];
    const float* a1 = (const float*)d_in[6];
    const float* W2 = (const float*)d_in[7];
    const float* b2 = (const float*)d_in[8];
    const float* g2 = (const float*)d_in[9];
    const float* be2 = (const float*)d_in[10];
    const float* a2 = (const float*)d_in[11];
    const float* We2d = (const float*)d_in[12];
    const float* Wd = (const float*)d_in[13];
    const float* bd = (const float*)d_in[14];
    const int* src = (const int*)d_in[15];
    const int* dst = (const int*)d_in[16];
    const int* mask_nodes = (const int*)d_in[17];

    char* w = (char*)d_ws;
    float* A = (float*)w;       w += (size_t)N * D * 4;
    float* Bf = (float*)w;      w += (size_t)N * D * 4;
    int* col = (int*)w;         w += (size_t)E * 4;
    int* row_ptr = (int*)w;     w += (size_t)(N + 1) * 4;
    int* cnt_src = (int*)w;     w += (size_t)N * 4;
    int* cnt_dst = (int*)w;     w += (size_t)N * 4;
    int* cursor = (int*)w;      w += (size_t)N * 4;
    int* mflag = (int*)w;       w += (size_t)N * 4;
    int* bsum = (int*)w;        w += 256 * 4;
    float* dinv_out = (float*)w; w += (size_t)N * 4;
    float* dinv_in = (float*)w;  w += (size_t)N * 4;
    float* Wr1 = (float*)w;     w += (size_t)D * D * 4;
    float* Wr2 = (float*)w;     w += (size_t)D * D * 4;
    float* WrE = (float*)w;     w += (size_t)D * D * 4;
    float* WrD = (float*)w;     w += (size_t)D * D * 4;

    // zero: cnt_src, cnt_dst, cursor, mflag (contiguous 4*N ints) + output scalar
    hipMemsetAsync(cnt_src, 0, (size_t)4 * N * 4, stream);
    hipMemsetAsync(d_out, 0, sizeof(float), stream);

    k_count<<<(E + 255) / 256, 256, 0, stream>>>(src, dst, cnt_src, cnt_dst);
    k_scan1<<<NB_SCAN, 256, 0, stream>>>(cnt_dst, bsum);
    k_scan2<<<1, 64, 0, stream>>>(bsum, row_ptr);
    k_scan3<<<NB_SCAN, 256, 0, stream>>>(cnt_dst, bsum, row_ptr);
    k_fill<<<(E + 255) / 256, 256, 0, stream>>>(src, dst, row_ptr, cursor, col);
    k_dinv<<<(N + 255) / 256, 256, 0, stream>>>(cnt_src, cnt_dst, dinv_out, dinv_in);
    k_mflag<<<(MASKN + 255) / 256, 256, 0, stream>>>(mask_nodes, mflag);
    k_tr4<<<16, 256, 0, stream>>>((const float4*)W1, (float4*)Wr1);
    k_tr4<<<16, 256, 0, stream>>>((const float4*)W2, (float4*)Wr2);
    k_tr4<<<16, 256, 0, stream>>>((const float4*)We2d, (float4*)WrE);
    k_tr4<<<16, 256, 0, stream>>>((const float4*)Wd, (float4*)WrD);
    k_prep<<<(N * 32 + 255) / 256, 256, 0, stream>>>((const float4*)x, (const float4*)tok,
                                                     mflag, dinv_out, (float4*)A);
    dim3 bs(64, 4);
    int ndense = N / 8;     // 6250
    int nloss = MASKN / 8;  // 3125
    // conv1: agg
    k_spmm<<<(N + 3) / 4, bs, 0, stream>>>((const float4*)A, (float4*)Bf, row_ptr, col, nullptr, N);
    // conv1 epilogue: fc + in-deg norm + LN + PReLU, pre-scale by deg_out^-0.5
    k_dense<true, true, false><<<ndense, 128, 0, stream>>>(
        Bf, A, (const float4*)Wr1, b1, g1, be1, a1, dinv_in, dinv_out, nullptr);
    // conv2: agg
    k_spmm<<<(N + 3) / 4, bs, 0, stream>>>((const float4*)A, (float4*)Bf, row_ptr, col, nullptr, N);
    // conv2 epilogue: h2 (unscaled)
    k_dense<true, false, false><<<ndense, 128, 0, stream>>>(
        Bf, A, (const float4*)Wr2, b2, g2, be2, a2, dinv_in, dinv_out, nullptr);
    // encoder_to_decoder + re-mask + pre-scale for conv3
    k_dense<false, true, true><<<ndense, 128, 0, stream>>>(
        A, Bf, (const float4*)WrE, nullptr, nullptr, nullptr, nullptr,
        dinv_in, dinv_out, mflag);
    // conv3: agg, masked rows only
    k_spmm<<<(MASKN + 3) / 4, bs, 0, stream>>>((const float4*)Bf, (float4*)A, row_ptr, col,
                                               mask_nodes, MASKN);
    // decoder fc + SCE loss
    k_loss<<<nloss, 128, 0, stream>>>(A, x, (const float4*)WrD, bd,
                                      dinv_in, mask_nodes, (float*)d_out);
}

// Round 6
// 462.972 us; speedup vs baseline: 9.5972x; 1.2023x over previous
//
#include <hip/hip_runtime.h>

constexpr int N = 50000;
constexpr int E = 800000;
constexpr int D = 128;
constexpr int MASKN = 25000;
constexpr int CAP = 96; // bucket capacity; deg ~ Poisson(16), P(>96) ~ 0

typedef _Float16 half8 __attribute__((ext_vector_type(8)));
typedef _Float16 half4 __attribute__((ext_vector_type(4)));

#define DOT_STEP(w, a, acc)                                                    \
    acc = fmaf(w.x, a.x, acc);                                                 \
    acc = fmaf(w.y, a.y, acc);                                                 \
    acc = fmaf(w.z, a.z, acc);                                                 \
    acc = fmaf(w.w, a.w, acc)

#define ROW8(X) X(0) X(1) X(2) X(3) X(4) X(5) X(6) X(7)

// ---------------- one-pass bucket-CSR build ----------------
// cnt_src: out-degree histogram. cursor: in-degree histogram AND bucket cursor.

__global__ void k_build(const int* __restrict__ src, const int* __restrict__ dst,
                        int* __restrict__ cnt_src, int* __restrict__ cursor,
                        int* __restrict__ col) {
    int e = blockIdx.x * blockDim.x + threadIdx.x;
    if (e < E) {
        int s = src[e], d = dst[e];
        atomicAdd(&cnt_src[s], 1);
        int p = atomicAdd(&cursor[d], 1);
        col[(size_t)d * CAP + p] = s;
    }
}

__global__ void k_dinv(const int* __restrict__ cs, const int* __restrict__ cd,
                       float* __restrict__ dinv_out, float* __restrict__ dinv_in) {
    int i = blockIdx.x * blockDim.x + threadIdx.x;
    if (i < N) {
        int a = cs[i] > 1 ? cs[i] : 1;
        int b = cd[i] > 1 ? cd[i] : 1;
        dinv_out[i] = rsqrtf((float)a);
        dinv_in[i] = rsqrtf((float)b);
    }
}

__global__ void k_mflag(const int* __restrict__ mask_nodes, int* __restrict__ mflag) {
    int i = blockIdx.x * blockDim.x + threadIdx.x;
    if (i < MASKN) mflag[mask_nodes[i]] = 1;
}

// ---------------- W transpose at float4 granularity: Wr4[k4*128+o] = W4[o*32+k4]

__global__ void k_tr4(const float4* __restrict__ W4, float4* __restrict__ Wr4) {
    int idx = blockIdx.x * 256 + threadIdx.x; // 4096 total
    int o = idx >> 5, k4 = idx & 31;
    Wr4[k4 * 128 + o] = W4[idx];
}

// ---------------- feature prep: masked x scaled by deg_out^-0.5, fp16 out ----

__global__ void k_prep(const float4* __restrict__ x, const float4* __restrict__ tok,
                       const int* __restrict__ mflag, const float* __restrict__ dinv_out,
                       half4* __restrict__ Ah4) {
    int i = blockIdx.x * blockDim.x + threadIdx.x; // over N*32 float4s
    if (i < N * 32) {
        int row = i >> 5;
        int c = i & 31;
        float s = dinv_out[row];
        float4 v = mflag[row] ? tok[c] : x[i];
        half4 h;
        h[0] = (_Float16)(v.x * s);
        h[1] = (_Float16)(v.y * s);
        h[2] = (_Float16)(v.z * s);
        h[3] = (_Float16)(v.w * s);
        Ah4[i] = h;
    }
}

// ---------------- SpMM: B[row] = sum over bucket neighbors of Ah[col] ----------
// 256 thr = 4 waves, one row/wave; quarter-wave (16 lanes x 16B) per edge:
// 4 edges per vector instruction, 2 gathers in flight, f32 accumulate.

__launch_bounds__(256)
__global__ void k_spmm(const half8* __restrict__ Ah8, float4* __restrict__ B4,
                       const int* __restrict__ deg, const int* __restrict__ col,
                       const int* __restrict__ rows, int nrows) {
    int wv = threadIdx.x >> 6, lane = threadIdx.x & 63;
    int q = lane >> 4, j = lane & 15;
    int rr = blockIdx.x * 4 + wv;
    if (rr >= nrows) return;
    int row = rows ? rows[rr] : rr;
    int dg = deg[row];
    const int* crow = col + (size_t)row * CAP;
    float a0 = 0.f, a1 = 0.f, a2 = 0.f, a3 = 0.f;
    float a4 = 0.f, a5 = 0.f, a6 = 0.f, a7 = 0.f;
    int e = q;
    for (; e + 4 < dg; e += 8) {
        int c0 = crow[e], c1 = crow[e + 4];
        half8 h0 = Ah8[(size_t)c0 * 16 + j];
        half8 h1 = Ah8[(size_t)c1 * 16 + j];
#define SP_ACC(i) a##i += (float)h0[i]; a##i += (float)h1[i];
        ROW8(SP_ACC)
#undef SP_ACC
    }
    if (e < dg) {
        int c0 = crow[e];
        half8 h0 = Ah8[(size_t)c0 * 16 + j];
#define SP_ACC1(i) a##i += (float)h0[i];
        ROW8(SP_ACC1)
#undef SP_ACC1
    }
#pragma unroll
    for (int o = 16; o <= 32; o <<= 1) {
#define SP_SHFL(i) a##i += __shfl_xor(a##i, o);
        ROW8(SP_SHFL)
#undef SP_SHFL
    }
    if (q == 0) {
        B4[(size_t)row * 32 + j * 2] = make_float4(a0, a1, a2, a3);
        B4[(size_t)row * 32 + j * 2 + 1] = make_float4(a4, a5, a6, a7);
    }
}

// ---------------- dense: thread t = output col, 8 rows/block, coalesced Wr ----

template <bool LN, bool SCALE_OUT, bool MASK_ZERO, bool OUT_HALF>
__launch_bounds__(128)
__global__ void k_dense(const float* __restrict__ in, float* __restrict__ out,
                        _Float16* __restrict__ outh,
                        const float4* __restrict__ Wr4, const float* __restrict__ bias,
                        const float* __restrict__ g, const float* __restrict__ be,
                        const float* __restrict__ aP, const float* __restrict__ dinv_in,
                        const float* __restrict__ dinv_out, const int* __restrict__ mflag) {
    __shared__ float sh[8 * 128];
    __shared__ float red[32];
    int t = threadIdx.x;
    int r0 = blockIdx.x * 8; // N % 8 == 0
    {
        const float4* inb = (const float4*)(in + (size_t)r0 * 128);
        float4* s4 = (float4*)sh;
        s4[t] = inb[t];
        s4[t + 128] = inb[t + 128];
    }
    __syncthreads();
    const float4* sh4 = (const float4*)sh;
    float acc0 = 0.f, acc1 = 0.f, acc2 = 0.f, acc3 = 0.f;
    float acc4 = 0.f, acc5 = 0.f, acc6 = 0.f, acc7 = 0.f;
#pragma unroll 2
    for (int k4 = 0; k4 < 32; ++k4) {
        float4 w = Wr4[k4 * 128 + t];
#define DENSE_FMA(i)                                                           \
        {                                                                      \
            float4 a = sh4[i * 32 + k4];                                       \
            DOT_STEP(w, a, acc##i);                                            \
        }
        ROW8(DENSE_FMA)
#undef DENSE_FMA
    }
    float v0 = acc0, v1 = acc1, v2 = acc2, v3 = acc3;
    float v4 = acc4, v5 = acc5, v6 = acc6, v7 = acc7;
    if constexpr (LN) {
        float bt = bias[t];
#define LN_PRE(i) v##i = (v##i + bt) * dinv_in[r0 + i];
        ROW8(LN_PRE)
#undef LN_PRE
#define LN_DECL(i) float s##i = v##i, q##i = v##i * v##i;
        ROW8(LN_DECL)
#undef LN_DECL
#pragma unroll
        for (int o = 32; o > 0; o >>= 1) {
#define LN_SHFL(i)                                                             \
            s##i += __shfl_xor(s##i, o);                                       \
            q##i += __shfl_xor(q##i, o);
            ROW8(LN_SHFL)
#undef LN_SHFL
        }
        if ((t & 63) == 0) {
            int wv = t >> 6;
#define LN_RED(i)                                                              \
            red[wv * 16 + 2 * i] = s##i;                                       \
            red[wv * 16 + 2 * i + 1] = q##i;
            ROW8(LN_RED)
#undef LN_RED
        }
        __syncthreads();
        float gt = g[t], bet = be[t], alpha = aP[0];
#define LN_ROW(i)                                                              \
        {                                                                      \
            float S = red[2 * i] + red[16 + 2 * i];                            \
            float Q = red[2 * i + 1] + red[16 + 2 * i + 1];                    \
            float mu = S * (1.f / D);                                          \
            float var = Q * (1.f / D) - mu * mu;                               \
            float rs = rsqrtf(var + 1e-5f);                                    \
            v##i = (v##i - mu) * rs * gt + bet;                                \
            v##i = v##i >= 0.f ? v##i : alpha * v##i;                          \
        }
        ROW8(LN_ROW)
#undef LN_ROW
    }
    if constexpr (MASK_ZERO) {
#define MZ(i) if (mflag[r0 + i]) v##i = 0.f;
        ROW8(MZ)
#undef MZ
    }
    if constexpr (SCALE_OUT) {
#define SO(i) v##i *= dinv_out[r0 + i];
        ROW8(SO)
#undef SO
    }
    if constexpr (OUT_HALF) {
#define STOREH(i) outh[(size_t)(r0 + i) * 128 + t] = (_Float16)v##i;
        ROW8(STOREH)
#undef STOREH
    } else {
#define STORE(i) out[(size_t)(r0 + i) * 128 + t] = v##i;
        ROW8(STORE)
#undef STORE
    }
}

// decoder fc + degnorm + SCE loss over masked rows, same coalesced-W structure
__launch_bounds__(128)
__global__ void k_loss(const float* __restrict__ agg, const float* __restrict__ x,
                       const float4* __restrict__ Wr4, const float* __restrict__ bd,
                       const float* __restrict__ dinv_in, const int* __restrict__ mask_nodes,
                       float* __restrict__ outp) {
    __shared__ float sh[8 * 128];
    __shared__ float red[48];
    __shared__ int shm[8];
    int t = threadIdx.x;
    int i0 = blockIdx.x * 8; // MASKN % 8 == 0
    if (t < 8) shm[t] = mask_nodes[i0 + t];
    __syncthreads();
#pragma unroll
    for (int i = 0; i < 8; ++i) sh[i * 128 + t] = agg[(size_t)shm[i] * 128 + t];
    __syncthreads();
    const float4* sh4 = (const float4*)sh;
    float acc0 = 0.f, acc1 = 0.f, acc2 = 0.f, acc3 = 0.f;
    float acc4 = 0.f, acc5 = 0.f, acc6 = 0.f, acc7 = 0.f;
#pragma unroll 2
    for (int k4 = 0; k4 < 32; ++k4) {
        float4 w = Wr4[k4 * 128 + t];
#define LOSS_FMA(i)                                                            \
        {                                                                      \
            float4 a = sh4[i * 32 + k4];                                       \
            DOT_STEP(w, a, acc##i);                                            \
        }
        ROW8(LOSS_FMA)
#undef LOSS_FMA
    }
    float bt = bd[t];
#define LOSS_RXC(i)                                                            \
    float r##i = (acc##i + bt) * dinv_in[shm[i]];                              \
    float xv##i = x[(size_t)shm[i] * 128 + t];                                 \
    float a##i = r##i * r##i, b##i = xv##i * xv##i, c##i = r##i * xv##i;
    ROW8(LOSS_RXC)
#undef LOSS_RXC
#pragma unroll
    for (int o = 32; o > 0; o >>= 1) {
#define LOSS_SHFL(i)                                                           \
        a##i += __shfl_xor(a##i, o);                                           \
        b##i += __shfl_xor(b##i, o);                                           \
        c##i += __shfl_xor(c##i, o);
        ROW8(LOSS_SHFL)
#undef LOSS_SHFL
    }
    if ((t & 63) == 0) {
        int wv = t >> 6;
#define LOSS_RED(i)                                                            \
        red[wv * 24 + 3 * i] = a##i;                                           \
        red[wv * 24 + 3 * i + 1] = b##i;                                       \
        red[wv * 24 + 3 * i + 2] = c##i;
        ROW8(LOSS_RED)
#undef LOSS_RED
    }
    __syncthreads();
    if (t == 0) {
        float sum = 0.f;
#pragma unroll
        for (int i = 0; i < 8; ++i) {
            float A_ = red[3 * i] + red[24 + 3 * i];
            float B_ = red[3 * i + 1] + red[24 + 3 * i + 1];
            float C_ = red[3 * i + 2] + red[24 + 3 * i + 2];
            float nr = fmaxf(sqrtf(A_), 1e-12f);
            float nx = fmaxf(sqrtf(B_), 1e-12f);
            float term = 1.f - C_ / (nr * nx);
            sum += term * term;
        }
        atomicAdd(outp, sum * (1.f / MASKN));
    }
}

// ---------------- launch ----------------

extern "C" void kernel_launch(void* const* d_in, const int* in_sizes, int n_in,
                              void* d_out, int out_size, void* d_ws, size_t ws_size,
                              hipStream_t stream) {
    const float* x = (const float*)d_in[0];
    const float* tok = (const float*)d_in[1];
    const float* W1 = (const float*)d_in[2];
    const float* b1 = (const float*)d_in[3];
    const float* g1 = (const float*)d_in[4];
    const float* be1 = (const float*)d_in[5];
    const float* a1 = (const float*)d_in[6];
    const float* W2 = (const float*)d_in[7];
    const float* b2 = (const float*)d_in[8];
    const float* g2 = (const float*)d_in[9];
    const float* be2 = (const float*)d_in[10];
    const float* a2 = (const float*)d_in[11];
    const float* We2d = (const float*)d_in[12];
    const float* Wd = (const float*)d_in[13];
    const float* bd = (const float*)d_in[14];
    const int* src = (const int*)d_in[15];
    const int* dst = (const int*)d_in[16];
    const int* mask_nodes = (const int*)d_in[17];

    char* w = (char*)d_ws;
    _Float16* Ah = (_Float16*)w; w += (size_t)N * D * 2;
    float* Bf = (float*)w;       w += (size_t)N * D * 4;
    float* Hf = (float*)w;       w += (size_t)N * D * 4;
    int* col = (int*)w;          w += (size_t)N * CAP * 4;
    int* cnt_src = (int*)w;      w += (size_t)N * 4;
    int* cursor = (int*)w;       w += (size_t)N * 4; // becomes deg_in
    int* mflag = (int*)w;        w += (size_t)N * 4;
    float* dinv_out = (float*)w; w += (size_t)N * 4;
    float* dinv_in = (float*)w;  w += (size_t)N * 4;
    float* Wr1 = (float*)w;      w += (size_t)D * D * 4;
    float* Wr2 = (float*)w;      w += (size_t)D * D * 4;
    float* WrE = (float*)w;      w += (size_t)D * D * 4;
    float* WrD = (float*)w;      w += (size_t)D * D * 4;

    // zero cnt_src, cursor, mflag (contiguous 3*N ints) + output scalar
    hipMemsetAsync(cnt_src, 0, (size_t)3 * N * 4, stream);
    hipMemsetAsync(d_out, 0, sizeof(float), stream);

    k_build<<<(E + 255) / 256, 256, 0, stream>>>(src, dst, cnt_src, cursor, col);
    k_dinv<<<(N + 255) / 256, 256, 0, stream>>>(cnt_src, cursor, dinv_out, dinv_in);
    k_mflag<<<(MASKN + 255) / 256, 256, 0, stream>>>(mask_nodes, mflag);
    k_tr4<<<16, 256, 0, stream>>>((const float4*)W1, (float4*)Wr1);
    k_tr4<<<16, 256, 0, stream>>>((const float4*)W2, (float4*)Wr2);
    k_tr4<<<16, 256, 0, stream>>>((const float4*)We2d, (float4*)WrE);
    k_tr4<<<16, 256, 0, stream>>>((const float4*)Wd, (float4*)WrD);
    k_prep<<<(N * 32 + 255) / 256, 256, 0, stream>>>((const float4*)x, (const float4*)tok,
                                                     mflag, dinv_out, (half4*)Ah);
    int ndense = N / 8;     // 6250
    int nloss = MASKN / 8;  // 3125
    int nspmm = (N + 3) / 4;
    // conv1: agg (fp16 gather)
    k_spmm<<<nspmm, 256, 0, stream>>>((const half8*)Ah, (float4*)Bf, cursor, col, nullptr, N);
    // conv1 epilogue -> fp16, pre-scaled by deg_out^-0.5
    k_dense<true, true, false, true><<<ndense, 128, 0, stream>>>(
        Bf, nullptr, Ah, (const float4*)Wr1, b1, g1, be1, a1, dinv_in, dinv_out, nullptr);
    // conv2: agg
    k_spmm<<<nspmm, 256, 0, stream>>>((const half8*)Ah, (float4*)Bf, cursor, col, nullptr, N);
    // conv2 epilogue: h2 (f32)
    k_dense<true, false, false, false><<<ndense, 128, 0, stream>>>(
        Bf, Hf, nullptr, (const float4*)Wr2, b2, g2, be2, a2, dinv_in, dinv_out, nullptr);
    // encoder_to_decoder + re-mask + pre-scale -> fp16
    k_dense<false, true, true, true><<<ndense, 128, 0, stream>>>(
        Hf, nullptr, Ah, (const float4*)WrE, nullptr, nullptr, nullptr, nullptr,
        dinv_in, dinv_out, mflag);
    // conv3: agg, masked rows only
    k_spmm<<<(MASKN + 3) / 4, 256, 0, stream>>>((const half8*)Ah, (float4*)Bf, cursor, col,
                                                mask_nodes, MASKN);
    // decoder fc + SCE loss
    k_loss<<<nloss, 128, 0, stream>>>(Bf, x, (const float4*)WrD, bd,
                                      dinv_in, mask_nodes, (float*)d_out);
}